// Round 15
// baseline (63.060 us; speedup 1.0000x reference)
//
#include <hip/hip_runtime.h>
#include <hip/hip_bf16.h>
#include <math.h>

#define NROW 256
#define DIM  65536
#define NBLK 64             // split-K blocks (K=1024 each)
#define LSTR 264            // LDS row stride in ushorts (256 + 8 pad)
#define PSP  65600          // partial stride in ushorts (65536 + 64 pad)

typedef __attribute__((ext_vector_type(8))) short short8;
typedef __attribute__((ext_vector_type(4))) float f32x4;
typedef __attribute__((ext_vector_type(4))) float ef4;        // nt-compatible
typedef __attribute__((ext_vector_type(2))) unsigned int eu2;
typedef unsigned int       u32t;
typedef unsigned long long u64t;

__device__ __forceinline__ float bf2f(ushort h) {
    u32t u = ((u32t)h) << 16;
    return __builtin_bit_cast(float, u);
}
// packed fp32x2 -> bf16x2 (v_cvt_pk_bf16_f32, RNE)
__device__ __forceinline__ u32t pk2(float lo, float hi) {
    __hip_bfloat162 h = __float22bfloat162_rn(make_float2(lo, hi));
    u32t r; __builtin_memcpy(&r, &h, 4); return r;
}

// ---------------------------------------------------------------------------
// Split-K MFMA GEMM, P=64 (traffic-minimized): block s owns K=[s*1024,+1024),
// processed as 4 staged sub-slices of 256 k. Partial round-trip shrinks
// 66 MB -> 16 MB (we are starved to ~1.5 TB/s by the harness poison-fill's
// memory-side drain; bytes are the only lever). Per sub-slice: coalesced
// 1 KB row reads (nt - read-once), cvt_pk -> LDS bf16, barrier, 8 MFMA
// k-steps into persistent acc, barrier. Epilogue: LDS transpose -> coalesced
// stores; G symmetric => storing G^T in plain [i][j] IS G.
// ---------------------------------------------------------------------------
__global__ __launch_bounds__(512) void gemm_k(const float* __restrict__ E,
                                              ushort* __restrict__ part) {
    const int s    = blockIdx.x;
    const int tid  = threadIdx.x;
    const int lane = tid & 63;
    const int wid  = tid >> 6;
    const int wr   = wid >> 2;          // 0..1 -> 128-row band
    const int wc   = wid & 3;           // 0..3 -> 64-col band
    const int r15  = lane & 15;
    const int kgi  = lane >> 4;         // 0..3 -> 8-k slice within k=32

    __shared__ ushort es[NROW][LSTR];   // 135 KB; staging, then transpose buf

    f32x4 acc[8][4];
    #pragma unroll
    for (int m = 0; m < 8; ++m)
        #pragma unroll
        for (int n = 0; n < 4; ++n) acc[m][n] = (f32x4){0.f, 0.f, 0.f, 0.f};

    const int wrow = wid * 32;

    for (int it = 0; it < 4; ++it) {
        const size_t kb = (size_t)s * 1024 + (size_t)it * 256 + lane * 4;

        // stage: 32 rows/wave, 1 KB contiguous per row-instruction, batches
        // of 8 (<=64 staged VGPRs live alongside 128 acc)
        ef4 va[8], vb[8];
        auto LD = [&](int g, ef4* d) {
            #pragma unroll
            for (int u = 0; u < 8; ++u) {
                const int row = wrow + g * 8 + u;
                d[u] = __builtin_nontemporal_load(
                    (const ef4*)(E + ((size_t)row << 16) + kb));
            }
        };
        auto PR = [&](int g, const ef4* d) {
            #pragma unroll
            for (int u = 0; u < 8; ++u) {
                const int row = wrow + g * 8 + u;
                eu2 wv;
                wv.x = pk2(d[u].x, d[u].y);
                wv.y = pk2(d[u].z, d[u].w);
                *(eu2*)&es[row][lane * 4] = wv;
            }
        };
        LD(0, va); LD(1, vb); PR(0, va);
        LD(2, va); PR(1, vb);
        LD(3, vb); PR(2, va); PR(3, vb);

        __syncthreads();                // tile staged

        #pragma unroll
        for (int kk = 0; kk < 8; ++kk) {
            const int ko = kk * 32 + kgi * 8;
            short8 af[8], bfr[4];
            #pragma unroll
            for (int m = 0; m < 8; ++m)
                af[m] = *(const short8*)&es[wr * 128 + m * 16 + r15][ko];
            #pragma unroll
            for (int n = 0; n < 4; ++n)
                bfr[n] = *(const short8*)&es[wc * 64 + n * 16 + r15][ko];
            #pragma unroll
            for (int m = 0; m < 8; ++m)
                #pragma unroll
                for (int n = 0; n < 4; ++n)
                    acc[m][n] = __builtin_amdgcn_mfma_f32_16x16x32_bf16(
                        af[m], bfr[n], acc[m][n], 0, 0, 0);
        }
        __syncthreads();                // frag reads done; es reusable
    }

    // ---------------- epilogue: LDS transpose ----------------
    const int rq = (lane >> 4) * 4;     // row-quad base within 16-row block
    #pragma unroll
    for (int m = 0; m < 8; ++m)
        #pragma unroll
        for (int n = 0; n < 4; ++n) {
            const int col  = wc * 64 + n * 16 + r15;
            const int rowb = wr * 128 + m * 16 + rq;
            eu2 wv;
            wv.x = pk2(acc[m][n][0], acc[m][n][1]);
            wv.y = pk2(acc[m][n][2], acc[m][n][3]);
            *(eu2*)&es[col][rowb] = wv;   // es viewed as [col][row]
        }
    __syncthreads();

    // coalesced store-out (cached - reduce re-reads): wave w streams 32 cols
    ushort* pb = part + (size_t)s * PSP;
    #pragma unroll
    for (int i = 0; i < 32; ++i) {
        const int col = wid * 32 + i;
        const eu2 q = *(const eu2*)&es[col][lane * 4];
        *(eu2*)(pb + col * 256 + lane * 4) = q;
    }
}

// ---------------------------------------------------------------------------
// Reduce 64 bf16 partials -> Gn (fp32, plain [i*256+j]). One position per
// thread; 4 fixed-order groups of 16 (deterministic tree). Also zeroes the
// fixed-point accumulator for row_loss (stream-ordered).
// ---------------------------------------------------------------------------
__global__ __launch_bounds__(256) void reduce_k(const ushort* __restrict__ part,
                                                float* __restrict__ Gn,
                                                u64t* __restrict__ acc,
                                                u32t* __restrict__ cnt) {
    if (blockIdx.x == 0 && threadIdx.x == 0) { *acc = 0ull; *cnt = 0u; }

    const int pos = blockIdx.x * 256 + threadIdx.x;   // 0..65535
    const ushort* base = part + pos;

    float g[4];
    #pragma unroll
    for (int q = 0; q < 4; ++q) {
        float a = 0.f;
        #pragma unroll
        for (int u = 0; u < 16; ++u)
            a += bf2f(base[(size_t)(q * 16 + u) * PSP]);
        g[q] = a;
    }
    Gn[pos] = (g[0] + g[1]) + (g[2] + g[3]);
}

// ---------------------------------------------------------------------------
// Fused per-row softmax loss + deterministic final sum (fixed-point atomic,
// order-independent). PSD term provably 0 (AM-GM; clip at 0), omitted.
// ---------------------------------------------------------------------------
__global__ __launch_bounds__(256) void row_loss_k(const float* __restrict__ Gn,
                                                  const int* __restrict__ labels,
                                                  u64t* __restrict__ acc,
                                                  u32t* __restrict__ cnt,
                                                  float* __restrict__ out) {
    const int i = blockIdx.x;
    const int j = threadIdx.x;

    const float Gii = Gn[i * 256 + i];
    const float Gjj = Gn[j * 256 + j];
    const float Gij = Gn[i * 256 + j];
    const float d2 = fmaxf(Gii + Gjj - 2.0f * Gij, 0.0f);
    const bool diag = (j == i);
    const float sc = diag ? -3.0e38f : -sqrtf(d2);

    __shared__ float red0[4], red1[4];

    float m = sc;
    #pragma unroll
    for (int off = 32; off; off >>= 1) m = fmaxf(m, __shfl_xor(m, off, 64));
    const int w = j >> 6;
    if ((j & 63) == 0) red0[w] = m;
    __syncthreads();
    m = fmaxf(fmaxf(red0[0], red0[1]), fmaxf(red0[2], red0[3]));

    const float p  = diag ? 0.0f : expf(sc - m);
    const float nm = (labels[j] == labels[i]) ? p : 0.0f;

    float zs = p, ns = nm;
    #pragma unroll
    for (int off = 32; off; off >>= 1) {
        zs += __shfl_xor(zs, off, 64);
        ns += __shfl_xor(ns, off, 64);
    }
    __syncthreads();
    if ((j & 63) == 0) { red0[w] = zs; red1[w] = ns; }
    __syncthreads();
    if (j == 0) {
        const float Z = red0[0] + red0[1] + red0[2] + red0[3];
        const float N = red1[0] + red1[1] + red1[2] + red1[3];
        const float rl = logf(Z) - logf(N);          // >= 0 (N subset of Z)
        const long long q = llrintf(rl * 1048576.0f);
        atomicAdd(acc, (u64t)q);
        __threadfence();
        const u32t c = atomicAdd(cnt, 1u);
        if (c == NROW - 1) {
            __threadfence();
            const u64t tot = atomicAdd(acc, 0ull);
            out[0] = (float)((double)(long long)tot * (1.0 / 1048576.0) * 0.005);
        }
    }
}

extern "C" void kernel_launch(void* const* d_in, const int* in_sizes, int n_in,
                              void* d_out, int out_size, void* d_ws, size_t ws_size,
                              hipStream_t stream) {
    const float* E      = (const float*)d_in[0];
    const int*   labels = (const int*)d_in[1];
    float*       out    = (float*)d_out;

    ushort* part = (ushort*)d_ws;                         // NBLK * PSP ushorts
    float*  Gn   = (float*)((char*)d_ws + (size_t)NBLK * PSP * sizeof(ushort));
    u64t*   acc  = (u64t*)(Gn + 65536);
    u32t*   cnt  = (u32t*)(acc + 1);

    gemm_k    <<<NBLK, 512, 0, stream>>>(E, part);
    reduce_k  <<<256, 256, 0, stream>>>(part, Gn, acc, cnt);
    row_loss_k<<<NROW, 256, 0, stream>>>(Gn, labels, acc, cnt, out);
}

// Round 16
// 49.446 us; speedup vs baseline: 1.2753x; 1.2753x over previous
//
#include <hip/hip_runtime.h>
#include <hip/hip_bf16.h>
#include <math.h>

#define NROW  256
#define DIM   65536
#define LSTR  264           // LDS row stride in ushorts (256 + 8 pad)
#define NQUAD 8320          // packed upper-triangle quads: F(256)=2*64^2+2*64
#define PSTR  33344         // partial stride in ushorts (8320*4 + 64 pad)

typedef __attribute__((ext_vector_type(8))) short short8;
typedef __attribute__((ext_vector_type(4))) float f32x4;
typedef __attribute__((ext_vector_type(4))) float ef4;        // nt-compatible
typedef __attribute__((ext_vector_type(2))) unsigned int eu2;
typedef unsigned int       u32t;
typedef unsigned long long u64t;

__device__ __forceinline__ float bf2f(ushort h) {
    u32t u = ((u32t)h) << 16;
    return __builtin_bit_cast(float, u);
}
// packed fp32x2 -> bf16x2 (v_cvt_pk_bf16_f32, RNE)
__device__ __forceinline__ u32t pk2(float lo, float hi) {
    __hip_bfloat162 h = __float22bfloat162_rn(make_float2(lo, hi));
    u32t r; __builtin_memcpy(&r, &h, 4); return r;
}

// ---------------------------------------------------------------------------
// Split-K MFMA GEMM (structure = round 14) with TRIANGLE-PACKED partials:
// G symmetric -> store only quads (col, rowquad lane) with lane <= col>>2,
// at packed offset F(col)+lane, F(col)=2a^2+2a+b(a+1), col=4a+b.
// Partial round-trip: 33.6 MB -> 17.1 MB each way (time ∝ bytes law).
//  Stage:  wave w rows [w*32,+32); 1 instr = 64 lanes x 16 B = 1 KB
//          contiguous per row (nt - read once). cvt_pk -> ds_write_b64.
//  MFMA:   8 k-steps, 8 waves x (128x64), acc[8][4].
//  Epilogue: acc -> LDS transpose -> predicated packed column stores.
// ---------------------------------------------------------------------------
__global__ __launch_bounds__(512) void gemm_k(const float* __restrict__ E,
                                              ushort* __restrict__ part) {
    const int s    = blockIdx.x;
    const int tid  = threadIdx.x;
    const int lane = tid & 63;
    const int wid  = tid >> 6;
    const int wr   = wid >> 2;          // 0..1 -> 128-row band
    const int wc   = wid & 3;           // 0..3 -> 64-col band
    const int r15  = lane & 15;
    const int kgi  = lane >> 4;         // 0..3 -> 8-k slice within k=32

    __shared__ ushort es[NROW][LSTR];   // 135 KB; staging, then transpose buf

    // ---------------- stage: coalesced 1 KB row reads (nt) ----------------
    {
        const int wrow = wid * 32;
        ef4 v[32];
        #pragma unroll
        for (int i = 0; i < 32; ++i) {
            const int row = wrow + i;
            v[i] = __builtin_nontemporal_load(
                (const ef4*)(E + ((size_t)row << 16)
                               + (size_t)s * 256 + lane * 4));
        }
        #pragma unroll
        for (int i = 0; i < 32; ++i) {
            const int row = wrow + i;
            eu2 wv;
            wv.x = pk2(v[i].x, v[i].y);
            wv.y = pk2(v[i].z, v[i].w);
            *(eu2*)&es[row][lane * 4] = wv;
        }
    }
    __syncthreads();

    // ---------------- MFMA: 8 k-steps of K=32 ----------------
    f32x4 acc[8][4];
    #pragma unroll
    for (int m = 0; m < 8; ++m)
        #pragma unroll
        for (int n = 0; n < 4; ++n) acc[m][n] = (f32x4){0.f, 0.f, 0.f, 0.f};

    #pragma unroll
    for (int kk = 0; kk < 8; ++kk) {
        const int ko = kk * 32 + kgi * 8;
        short8 af[8], bfr[4];
        #pragma unroll
        for (int m = 0; m < 8; ++m)
            af[m] = *(const short8*)&es[wr * 128 + m * 16 + r15][ko];
        #pragma unroll
        for (int n = 0; n < 4; ++n)
            bfr[n] = *(const short8*)&es[wc * 64 + n * 16 + r15][ko];
        #pragma unroll
        for (int m = 0; m < 8; ++m)
            #pragma unroll
            for (int n = 0; n < 4; ++n)
                acc[m][n] = __builtin_amdgcn_mfma_f32_16x16x32_bf16(
                    af[m], bfr[n], acc[m][n], 0, 0, 0);
    }

    __syncthreads();    // all frag reads done; es reusable as [col][row]

    // ---------------- epilogue: LDS transpose ----------------
    const int rq = (lane >> 4) * 4;     // row-quad base within 16-row block
    #pragma unroll
    for (int m = 0; m < 8; ++m)
        #pragma unroll
        for (int n = 0; n < 4; ++n) {
            const int col  = wc * 64 + n * 16 + r15;
            const int rowb = wr * 128 + m * 16 + rq;
            eu2 wv;
            wv.x = pk2(acc[m][n][0], acc[m][n][1]);
            wv.y = pk2(acc[m][n][2], acc[m][n][3]);
            *(eu2*)&es[col][rowb] = wv;   // es viewed as [col][row]
        }
    __syncthreads();

    // packed triangle store-out: wave w streams cols [w*32, +32), lane covers
    // rows lane*4..+3, active iff lane <= col>>2 (quads above diag skipped;
    // sub-diagonal garbage inside the last quad is masked in reduce).
    ushort* pb = part + (size_t)s * PSTR;
    #pragma unroll
    for (int i = 0; i < 32; ++i) {
        const int col = wid * 32 + i;
        const int a = col >> 2, bq = col & 3;
        const int qbase = 2 * a * a + 2 * a + bq * (a + 1);
        if (lane <= a) {
            const eu2 q = *(const eu2*)&es[col][lane * 4];
            *(eu2*)(pb + (size_t)(qbase + lane) * 4) = q;
        }
    }
}

// ---------------------------------------------------------------------------
// Reduce packed-triangle partials -> Gn (fp32, plain [i*256+j], both mirror
// halves). One quad per thread: invert packing (Q -> col, rowquad), sum 256
// partials in fixed s order (deterministic), scatter-write Gn (L2-resident).
// Also zeroes the fixed-point accumulator for row_loss (stream-ordered).
// ---------------------------------------------------------------------------
__global__ __launch_bounds__(256) void reduce_k(const ushort* __restrict__ part,
                                                float* __restrict__ Gn,
                                                u64t* __restrict__ acc,
                                                u32t* __restrict__ cnt) {
    if (blockIdx.x == 0 && threadIdx.x == 0) { *acc = 0ull; *cnt = 0u; }

    const int Q = blockIdx.x * 256 + threadIdx.x;
    if (Q >= NQUAD) return;

    // invert F: block a such that 2a^2+2a <= Q < 2(a+1)^2+2(a+1)
    int a = (int)((sqrtf(1.0f + 2.0f * (float)Q) - 1.0f) * 0.5f);
    while (2 * (a + 1) * (a + 1) + 2 * (a + 1) <= Q) ++a;
    while (2 * a * a + 2 * a > Q) --a;
    const int rem = Q - (2 * a * a + 2 * a);
    const int bq  = rem / (a + 1);
    const int r   = rem - bq * (a + 1);
    const int col = 4 * a + bq;

    const ushort* base = part + (size_t)Q * 4;

    float f0 = 0.f, f1 = 0.f, f2 = 0.f, f3 = 0.f;
    for (int g = 0; g < 16; ++g) {
        eu2 v[16];
        #pragma unroll
        for (int u = 0; u < 16; ++u)
            v[u] = *(const eu2*)(base + (size_t)(g * 16 + u) * PSTR);
        #pragma unroll
        for (int u = 0; u < 16; ++u) {
            f0 += bf2f((ushort)(v[u].x & 0xffffu));
            f1 += bf2f((ushort)(v[u].x >> 16));
            f2 += bf2f((ushort)(v[u].y & 0xffffu));
            f3 += bf2f((ushort)(v[u].y >> 16));
        }
    }
    const float vals[4] = {f0, f1, f2, f3};
    #pragma unroll
    for (int e = 0; e < 4; ++e) {
        const int row = r * 4 + e;
        if (row <= col) {
            Gn[col * 256 + row] = vals[e];
            Gn[row * 256 + col] = vals[e];
        }
    }
}

// ---------------------------------------------------------------------------
// Fused per-row softmax loss + deterministic final sum (fixed-point atomic,
// order-independent). PSD term provably 0 (AM-GM; clip at 0), omitted.
// ---------------------------------------------------------------------------
__global__ __launch_bounds__(256) void row_loss_k(const float* __restrict__ Gn,
                                                  const int* __restrict__ labels,
                                                  u64t* __restrict__ acc,
                                                  u32t* __restrict__ cnt,
                                                  float* __restrict__ out) {
    const int i = blockIdx.x;
    const int j = threadIdx.x;

    const float Gii = Gn[i * 256 + i];
    const float Gjj = Gn[j * 256 + j];
    const float Gij = Gn[i * 256 + j];
    const float d2 = fmaxf(Gii + Gjj - 2.0f * Gij, 0.0f);
    const bool diag = (j == i);
    const float sc = diag ? -3.0e38f : -sqrtf(d2);

    __shared__ float red0[4], red1[4];

    float m = sc;
    #pragma unroll
    for (int off = 32; off; off >>= 1) m = fmaxf(m, __shfl_xor(m, off, 64));
    const int w = j >> 6;
    if ((j & 63) == 0) red0[w] = m;
    __syncthreads();
    m = fmaxf(fmaxf(red0[0], red0[1]), fmaxf(red0[2], red0[3]));

    const float p  = diag ? 0.0f : expf(sc - m);
    const float nm = (labels[j] == labels[i]) ? p : 0.0f;

    float zs = p, ns = nm;
    #pragma unroll
    for (int off = 32; off; off >>= 1) {
        zs += __shfl_xor(zs, off, 64);
        ns += __shfl_xor(ns, off, 64);
    }
    __syncthreads();
    if ((j & 63) == 0) { red0[w] = zs; red1[w] = ns; }
    __syncthreads();
    if (j == 0) {
        const float Z = red0[0] + red0[1] + red0[2] + red0[3];
        const float N = red1[0] + red1[1] + red1[2] + red1[3];
        const float rl = logf(Z) - logf(N);          // >= 0 (N subset of Z)
        const long long q = llrintf(rl * 1048576.0f);
        atomicAdd(acc, (u64t)q);
        __threadfence();
        const u32t c = atomicAdd(cnt, 1u);
        if (c == NROW - 1) {
            __threadfence();
            const u64t tot = atomicAdd(acc, 0ull);
            out[0] = (float)((double)(long long)tot * (1.0 / 1048576.0) * 0.005);
        }
    }
}

extern "C" void kernel_launch(void* const* d_in, const int* in_sizes, int n_in,
                              void* d_out, int out_size, void* d_ws, size_t ws_size,
                              hipStream_t stream) {
    const float* E      = (const float*)d_in[0];
    const int*   labels = (const int*)d_in[1];
    float*       out    = (float*)d_out;

    ushort* part = (ushort*)d_ws;                         // 256 * PSTR ushorts
    float*  Gn   = (float*)((char*)d_ws + (size_t)256 * PSTR * sizeof(ushort));
    u64t*   acc  = (u64t*)(Gn + 65536);
    u32t*   cnt  = (u32t*)(acc + 1);

    gemm_k    <<<256, 512, 0, stream>>>(E, part);
    reduce_k  <<<(NQUAD + 255) / 256, 256, 0, stream>>>(part, Gn, acc, cnt);
    row_loss_k<<<NROW, 256, 0, stream>>>(Gn, labels, acc, cnt, out);
}